// Round 1
// baseline (18499.379 us; speedup 1.0000x reference)
//
#include <hip/hip_runtime.h>

// ---------------------------------------------------------------------------
// RGCN (basis decomposition), 2 layers. N=50000, E=1e6, H=128, O=64, R=16.
// Strategy: bin edges by relation (counting sort, bins padded to 64-edge
// tiles). Per layer: one kernel; each block = 64 edges of one relation,
// gathers x[src] rows into LDS, tile-GEMMs against LDS-staged W[r], scales by
// norm, atomicAdds into h[dst]. Bias folded into h init; ReLU folded into
// layer-2 gather. fp32 everywhere (correctness baseline).
// ---------------------------------------------------------------------------

__global__ void compute_w(const float* __restrict__ comp, const float* __restrict__ V,
                          float* __restrict__ W, int IO) {
  int idx = blockIdx.x * blockDim.x + threadIdx.x;
  if (idx >= 16 * IO) return;
  int r = idx / IO, p = idx - r * IO;
  float s = 0.f;
#pragma unroll
  for (int b = 0; b < 16; b++) s = fmaf(comp[r * 16 + b], V[b * IO + p], s);
  W[idx] = s;
}

__global__ void hist_etype(const int* __restrict__ etype, int n, int* __restrict__ counts) {
  __shared__ int lc[16];
  if (threadIdx.x < 16) lc[threadIdx.x] = 0;
  __syncthreads();
  for (int i = blockIdx.x * blockDim.x + threadIdx.x; i < n; i += gridDim.x * blockDim.x)
    atomicAdd(&lc[etype[i]], 1);
  __syncthreads();
  if (threadIdx.x < 16) atomicAdd(&counts[threadIdx.x], lc[threadIdx.x]);
}

__global__ void make_offsets(const int* __restrict__ counts, int* __restrict__ offsets) {
  if (threadIdx.x == 0 && blockIdx.x == 0) {
    int acc = 0;
    for (int r = 0; r < 16; r++) { offsets[r] = acc; acc += (counts[r] + 63) & ~63; }
    offsets[16] = acc;
  }
}

// Counting-sort edges into bins; write binned src/dst/norm arrays so the edge
// kernel reads them coalesced. Pad slots keep the 0xFF (-1) fill.
__global__ void scatter_bins(const int* __restrict__ etype, const int* __restrict__ src,
                             const int* __restrict__ dst, const float* __restrict__ norm,
                             int n, const int* __restrict__ offsets, int* __restrict__ cursor,
                             int* __restrict__ sb, int* __restrict__ db, float* __restrict__ nb) {
  __shared__ int lc[16];
  __shared__ int lbase[16];
  const int t = threadIdx.x;
  for (int start = blockIdx.x * 256; start < n; start += gridDim.x * 256) {
    if (t < 16) lc[t] = 0;
    __syncthreads();
    int e = start + t;
    int r = -1, rank = 0;
    if (e < n) { r = etype[e]; rank = atomicAdd(&lc[r], 1); }
    __syncthreads();
    if (t < 16) { int c = lc[t]; lbase[t] = c > 0 ? atomicAdd(&cursor[t], c) : 0; }
    __syncthreads();
    if (e < n) {
      int p = offsets[r] + lbase[r] + rank;
      sb[p] = src[e]; db[p] = dst[e]; nb[p] = norm[e];
    }
    __syncthreads();
  }
}

__global__ void init_bias(float* __restrict__ H, const float* __restrict__ bias,
                          int total, int D) {
  int i = blockIdx.x * blockDim.x + threadIdx.x;
  if (i < total) H[i] = bias[i & (D - 1)];
}

// One block = one 64-edge tile of a single relation.
// LDS: xs[64][128] (gathered x rows) + ws[128][64] (W chunk) = 64 KB exactly.
// 256 threads, 4x4 micro-tile per thread over a 64(edge) x 64(out) tile.
template <int OUT_TOTAL, bool RELU_IN>
__launch_bounds__(256)
__global__ void edge_gemm_scatter(const float* __restrict__ X, const float* __restrict__ W,
                                  const int* __restrict__ sb, const int* __restrict__ db,
                                  const float* __restrict__ nb, const int* __restrict__ offsets,
                                  float* __restrict__ H) {
  __shared__ __align__(16) float xs[64][128];
  __shared__ __align__(16) float ws[128][64];
  const int base = blockIdx.x * 64;
  if (base >= offsets[16]) return;
  int r = 0;
#pragma unroll
  for (int i = 1; i < 16; i++)
    if (offsets[i] <= base) r = i;
  const int t = threadIdx.x;

  // gather 64 rows of X (float4-vectorized, coalesced)
#pragma unroll
  for (int c = 0; c < 8; c++) {
    int idx = c * 256 + t;
    int e = idx >> 5, k4 = idx & 31;
    int s = sb[base + e];
    float4 v = make_float4(0.f, 0.f, 0.f, 0.f);
    if (s >= 0) v = ((const float4*)(X + (size_t)s * 128))[k4];
    if (RELU_IN) {
      v.x = fmaxf(v.x, 0.f); v.y = fmaxf(v.y, 0.f);
      v.z = fmaxf(v.z, 0.f); v.w = fmaxf(v.w, 0.f);
    }
    *(float4*)&xs[e][k4 * 4] = v;
  }

  const float* Wr = W + (size_t)r * 128 * OUT_TOTAL;
  const int eg = t >> 4, og = t & 15;

#pragma unroll
  for (int oc = 0; oc < OUT_TOTAL / 64; oc++) {
    __syncthreads();  // xs ready (oc=0) / ws consumers done (oc>0)
    // stage W chunk [128][64]
#pragma unroll
    for (int c = 0; c < 8; c++) {
      int idx = c * 256 + t;
      int k = idx >> 4, o4 = idx & 15;
      *(float4*)&ws[k][o4 * 4] = ((const float4*)(Wr + k * OUT_TOTAL + oc * 64))[o4];
    }
    __syncthreads();

    float acc[4][4] = {};
#pragma unroll
    for (int k = 0; k < 128; k += 4) {
      float4 a[4], b[4];
#pragma unroll
      for (int ii = 0; ii < 4; ii++) a[ii] = *(const float4*)&xs[eg * 4 + ii][k];
#pragma unroll
      for (int kk = 0; kk < 4; kk++) b[kk] = *(const float4*)&ws[k + kk][og * 4];
#pragma unroll
      for (int ii = 0; ii < 4; ii++) {
        const float av[4] = {a[ii].x, a[ii].y, a[ii].z, a[ii].w};
#pragma unroll
        for (int kk = 0; kk < 4; kk++) {
          acc[ii][0] = fmaf(av[kk], b[kk].x, acc[ii][0]);
          acc[ii][1] = fmaf(av[kk], b[kk].y, acc[ii][1]);
          acc[ii][2] = fmaf(av[kk], b[kk].z, acc[ii][2]);
          acc[ii][3] = fmaf(av[kk], b[kk].w, acc[ii][3]);
        }
      }
    }

    // scale by norm and scatter-add to destination rows
#pragma unroll
    for (int ii = 0; ii < 4; ii++) {
      int ei = base + eg * 4 + ii;
      int d = db[ei];
      if (d >= 0) {
        float nm = nb[ei];
        float* hp = H + (size_t)d * OUT_TOTAL + oc * 64 + og * 4;
        atomicAdd(hp + 0, acc[ii][0] * nm);
        atomicAdd(hp + 1, acc[ii][1] * nm);
        atomicAdd(hp + 2, acc[ii][2] * nm);
        atomicAdd(hp + 3, acc[ii][3] * nm);
      }
    }
  }
}

extern "C" void kernel_launch(void* const* d_in, const int* in_sizes, int n_in,
                              void* d_out, int out_size, void* d_ws, size_t ws_size,
                              hipStream_t stream) {
  const int*   src   = (const int*)d_in[1];
  const int*   dst   = (const int*)d_in[2];
  const int*   etype = (const int*)d_in[3];
  const float* norm  = (const float*)d_in[4];
  const float* emb   = (const float*)d_in[5];
  const float* V1    = (const float*)d_in[6];
  const float* comp1 = (const float*)d_in[7];
  const float* bias1 = (const float*)d_in[8];
  const float* V2    = (const float*)d_in[9];
  const float* comp2 = (const float*)d_in[10];
  const float* bias2 = (const float*)d_in[11];
  float* out = (float*)d_out;

  const int N = in_sizes[0];   // 50000
  const int E = in_sizes[1];   // 1000000
  const int H = 128, O = 64, R = 16;
  const int NTILES = (E + 63) / 64 + R;  // upper bound on padded tiles
  const int EPAD = NTILES * 64;

  char* ws = (char*)d_ws;
  size_t off = 0;
  auto alloc = [&](size_t bytes) -> void* {
    void* p = ws + off;
    off += (bytes + 255) & ~(size_t)255;
    return p;
  };
  float* W1 = (float*)alloc(sizeof(float) * R * H * H);
  float* W2 = (float*)alloc(sizeof(float) * R * H * O);
  float* h1 = (float*)alloc(sizeof(float) * (size_t)N * H);
  int*   sb = (int*)alloc(sizeof(int) * EPAD);
  int*   db = (int*)alloc(sizeof(int) * EPAD);
  float* nb = (float*)alloc(sizeof(float) * EPAD);
  int*   meta = (int*)alloc(sizeof(int) * 64);
  int* counts = meta;
  int* cursor = meta + 16;
  int* offs   = meta + 32;

  hipMemsetAsync(meta, 0, 64 * sizeof(int), stream);
  hipMemsetAsync(sb, 0xFF, sizeof(int) * EPAD, stream);
  hipMemsetAsync(db, 0xFF, sizeof(int) * EPAD, stream);

  compute_w<<<(R * H * H + 255) / 256, 256, 0, stream>>>(comp1, V1, W1, H * H);
  compute_w<<<(R * H * O + 255) / 256, 256, 0, stream>>>(comp2, V2, W2, H * O);
  hist_etype<<<1024, 256, 0, stream>>>(etype, E, counts);
  make_offsets<<<1, 64, 0, stream>>>(counts, offs);
  scatter_bins<<<1024, 256, 0, stream>>>(etype, src, dst, norm, E, offs, cursor, sb, db, nb);

  init_bias<<<((size_t)N * H + 255) / 256, 256, 0, stream>>>(h1, bias1, N * H, H);
  edge_gemm_scatter<128, false><<<NTILES, 256, 0, stream>>>(emb, W1, sb, db, nb, offs, h1);
  init_bias<<<((size_t)N * O + 255) / 256, 256, 0, stream>>>(out, bias2, N * O, O);
  edge_gemm_scatter<64, true><<<NTILES, 256, 0, stream>>>(h1, W2, sb, db, nb, offs, out);
}